// Round 9
// baseline (252.566 us; speedup 1.0000x reference)
//
#include <hip/hip_runtime.h>

typedef short short8 __attribute__((ext_vector_type(8)));
typedef _Float16 half8 __attribute__((ext_vector_type(8)));
typedef _Float16 half2v __attribute__((ext_vector_type(2)));
typedef float floatx4 __attribute__((ext_vector_type(4)));

extern "C" __device__ _Float16 __ocml_exp2_f16(_Float16);

#define B_   8
#define N_   2048
#define FIN_ 64
#define H_   4
#define D_   32
#define HD_  128
#define ALPHA_ 0.2f
#define LOG2E_ 1.4426950408889634f

// ws layout (bytes):
//   WhF  f16 [B][H][64 chunk][2 dhalf][64 lane][8] @ 0      (4 MB)  frag-contiguous
//   src  fp32 [B][H][N] (x log2e)                  @ 4 MB   (256 KB)
//   dstb f16 [B][H][N] (x log2e)                   @ 4.25MB (128 KB)

// ---- prep: Wh = h@W; WhF fragment-layout f16, src/dst (x log2e) -------------
__global__ __launch_bounds__(256) void gat_prep4(
    const float* __restrict__ h, const float* __restrict__ W, const float* __restrict__ a,
    unsigned short* __restrict__ WhF, float* __restrict__ src, unsigned short* __restrict__ dstb)
{
    __shared__ float Ws[FIN_][HD_];
    __shared__ float hsT[FIN_][36];
    int bx = blockIdx.x;
    int b = bx >> 6;
    int n0 = (bx & 63) * 32;            // 32 graph nodes (j) per block
    int tid = threadIdx.x;

    #pragma unroll
    for (int it = 0; it < 8; ++it) {
        int idx = it * 256 + tid;
        int k = idx >> 5, c4 = (idx & 31) << 2;
        *(float4*)&Ws[k][c4] = *(const float4*)&W[k * HD_ + c4];
    }
    #pragma unroll
    for (int it = 0; it < 8; ++it) {
        int idx = it * 256 + tid;
        int r = idx >> 6, k = idx & 63;
        hsT[k][r] = h[((size_t)b * N_ + n0 + r) * FIN_ + k];
    }
    __syncthreads();

    int c = tid & 127;                  // output column = h*32+d
    int rq = tid >> 7;                  // 16-row half
    int hh = c >> 5, d = c & 31;
    float acc[16];
    #pragma unroll
    for (int r = 0; r < 16; ++r) acc[r] = 0.f;
    for (int k = 0; k < FIN_; ++k) {
        float wv = Ws[k][c];
        float4 h0 = *(const float4*)&hsT[k][rq * 16];
        float4 h1 = *(const float4*)&hsT[k][rq * 16 + 4];
        float4 h2 = *(const float4*)&hsT[k][rq * 16 + 8];
        float4 h3 = *(const float4*)&hsT[k][rq * 16 + 12];
        acc[0]  += h0.x * wv; acc[1]  += h0.y * wv; acc[2]  += h0.z * wv; acc[3]  += h0.w * wv;
        acc[4]  += h1.x * wv; acc[5]  += h1.y * wv; acc[6]  += h1.z * wv; acc[7]  += h1.w * wv;
        acc[8]  += h2.x * wv; acc[9]  += h2.y * wv; acc[10] += h2.z * wv; acc[11] += h2.w * wv;
        acc[12] += h3.x * wv; acc[13] += h3.y * wv; acc[14] += h3.z * wv; acc[15] += h3.w * wv;
    }

    // FragB write (f16): Wh[j=n0+rq*16+r][col c] -> WhF[b][hh][it][dhalf][g*16+n][e]
    {
        int half = d >> 4, n = d & 15;
        int j0 = n0 + rq * 16;
        int it0 = j0 >> 5;
        int g0 = (j0 >> 3) & 3;         // 0 or 2; spans g0, g0+1
        #pragma unroll
        for (int rr = 0; rr < 2; ++rr) {
            __attribute__((aligned(16))) unsigned pk4[4];
            #pragma unroll
            for (int q = 0; q < 4; ++q)
                pk4[q] = __builtin_bit_cast(unsigned,
                    __builtin_amdgcn_cvt_pkrtz(acc[rr * 8 + 2 * q], acc[rr * 8 + 2 * q + 1]));
            size_t fi = ((((size_t)b * H_ + hh) * 64 + it0) * 2 + half) * 64
                        + (size_t)(g0 + rr) * 16 + n;
            *(uint4*)&WhF[fi * 8] = *(uint4*)pk4;
        }
    }

    float a1v = a[hh * 64 + d];
    float a2v = a[hh * 64 + 32 + d];
    #pragma unroll
    for (int r = 0; r < 16; ++r) {
        float s1 = acc[r] * a1v;
        float s2 = acc[r] * a2v;
        #pragma unroll
        for (int off = 16; off >= 1; off >>= 1) {
            s1 += __shfl_xor(s1, off, 32);
            s2 += __shfl_xor(s2, off, 32);
        }
        if (d == 0) {
            int n = n0 + rq * 16 + r;
            src[(b * H_ + hh) * N_ + n] = s1 * LOG2E_;
            _Float16 hv = (_Float16)(s2 * LOG2E_);
            dstb[(b * H_ + hh) * N_ + n] = __builtin_bit_cast(unsigned short, hv);
        }
    }
}

// ---- main: ZERO barriers. Each lane reads its own adj words from global
// (L1-broadcast across the 4 waves); dsts staged per-wave (own head only,
// wave-local LDS ordering). 16 waves/CU free-run 64 chunks, depth-2 prefetch.
__global__ __launch_bounds__(256, 4) void gat_main20(
    const int* __restrict__ adj, const unsigned short* __restrict__ WhF,
    const float* __restrict__ src, const unsigned short* __restrict__ dstb,
    float* __restrict__ out)
{
    __shared__ unsigned short dsts[H_][N_];    // 16 KB; slice [h] owned by wave h

    int bx = blockIdx.x;
    int b  = bx >> 7;
    int i0 = (bx & 127) * 16;
    int tid = threadIdx.x;
    int wv = tid >> 6, l = tid & 63;

    int h = wv, g = l >> 4, m = l & 15;
    int g8 = g << 3;

    // per-wave dsts stage: wave h loads ONLY head h's 4 KB (coalesced 16B/lane).
    // No __syncthreads: only this wave reads dsts[h]; same-wave LDS is ordered.
    {
        const unsigned short* dsrcW = dstb + (size_t)(b * H_ + h) * N_;
        #pragma unroll
        for (int it = 0; it < 4; ++it)
            *(uint4*)&dsts[h][it * 512 + l * 8] =
                *(const uint4*)&dsrcW[it * 512 + l * 8];
    }

    // per-lane adj row pointer: lane (g,m) reads adj[i0+m][it*32 + g8 .. +8)
    const int* adjP = adj + ((size_t)(b * N_ + i0 + m)) * N_ + g8;

    _Float16 sv = (_Float16)src[(b * H_ + h) * N_ + i0 + m];
    half2v s2; s2[0] = sv; s2[1] = sv;
    const _Float16 alf = (_Float16)0.2f;
    // fragment-contiguous B: chunk c at offset c*1024 shorts
    const unsigned short* WhB =
        WhF + ((size_t)(b * H_ + h) * 64) * 1024 + l * 8;
    const unsigned short* dstH = &dsts[h][0];

    short8 onesS;
    #pragma unroll
    for (int q = 0; q < 8; ++q) onesS[q] = (short)0x3C00;  // f16 1.0
    half8 ones = __builtin_bit_cast(half8, onesS);

    floatx4 acc0 = {0.f, 0.f, 0.f, 0.f};
    floatx4 acc1 = {0.f, 0.f, 0.f, 0.f};
    floatx4 acc2 = {0.f, 0.f, 0.f, 0.f};

    // depth-2 prefetch on all three streams (chunks 0 and 1 in flight)
    int4 a0_a = *(const int4*)&adjP[0];
    int4 a1_a = *(const int4*)&adjP[4];
    int4 a0_b = *(const int4*)&adjP[32];
    int4 a1_b = *(const int4*)&adjP[36];
    short8 bf0_a = *(const short8*)&WhB[0];
    short8 bf1_a = *(const short8*)&WhB[512];
    short8 bf0_b = *(const short8*)&WhB[1024];
    short8 bf1_b = *(const short8*)&WhB[1536];
    uint4 dv_a = *(const uint4*)&dstH[g8];           // own-wave writes: lgkm-ordered
    uint4 dv_b = *(const uint4*)&dstH[32 + g8];

    // additive f16 mask pair {0,-inf} from two adj ints in {0,1}
    auto mkpair = [](int px, int py) -> unsigned {
        unsigned t = ((unsigned)px | ((unsigned)py << 16)) ^ 0x00010001u;
        return t * 0xFC00u;                          // no cross-half carry
    };

    #pragma unroll 4
    for (int it = 0; it < 64; ++it) {
        // prefetch chunk it+2 (adj offset clamped: adj buffer ends page-aligned)
        int itp = (it + 2 < 64) ? (it + 2) : 63;
        int4 a0_n = *(const int4*)&adjP[itp * 32];
        int4 a1_n = *(const int4*)&adjP[itp * 32 + 4];
        int fn = (it + 2) * 1024;                    // ws overread ok (into src)
        short8 bf0_n = *(const short8*)&WhB[fn];
        short8 bf1_n = *(const short8*)&WhB[fn + 512];
        int j2 = ((it + 2) << 5) + g8;
        uint4  dv_n = *(const uint4*)&dstH[(j2 < N_) ? j2 : g8];

        unsigned mk[4];
        mk[0] = mkpair(a0_a.x, a0_a.y);
        mk[1] = mkpair(a0_a.z, a0_a.w);
        mk[2] = mkpair(a1_a.x, a1_a.y);
        mk[3] = mkpair(a1_a.z, a1_a.w);

        const unsigned* du = (const unsigned*)&dv_a;
        __attribute__((aligned(16))) unsigned pk[4];
        #pragma unroll
        for (int c2 = 0; c2 < 4; ++c2) {
            half2v d2 = __builtin_bit_cast(half2v, du[c2]);
            half2v e2 = s2 + d2;                            // v_pk_add_f16
            e2 = e2 + __builtin_bit_cast(half2v, mk[c2]);   // + {0,-inf} mask
            half2v t2 = e2 * alf;                           // v_pk_mul_f16
            e2 = __builtin_elementwise_max(e2, t2);         // v_pk_max_f16 (lrelu)
            half2v x2;
            x2[0] = __ocml_exp2_f16(e2[0]);                 // exp2; -inf -> +0
            x2[1] = __ocml_exp2_f16(e2[1]);
            pk[c2] = __builtin_bit_cast(unsigned, x2);      // IS the A-frag pair
        }
        half8 af = __builtin_bit_cast(half8, *(uint4*)pk);
        acc0 = __builtin_amdgcn_mfma_f32_16x16x32_f16(
                   af, __builtin_bit_cast(half8, bf0_a), acc0, 0, 0, 0);
        acc1 = __builtin_amdgcn_mfma_f32_16x16x32_f16(
                   af, __builtin_bit_cast(half8, bf1_a), acc1, 0, 0, 0);
        acc2 = __builtin_amdgcn_mfma_f32_16x16x32_f16(af, ones, acc2, 0, 0, 0);
        // rotate depth-2 pipelines (unrolled -> mostly renaming)
        a0_a = a0_b; a0_b = a0_n;
        a1_a = a1_b; a1_b = a1_n;
        bf0_a = bf0_b; bf0_b = bf0_n;
        bf1_a = bf1_b; bf1_b = bf1_n;
        dv_a = dv_b;   dv_b = dv_n;
    }

    // in-register finalize: acc2 = full row sum (C/D: col=m, row=g*4+r)
    #pragma unroll
    for (int r = 0; r < 4; ++r) {
        float inv = 1.f / acc2[r];
        size_t o = ((size_t)b * N_ + i0 + g * 4 + r) * HD_ + h * 32 + m;
        out[o]      = acc0[r] * inv;
        out[o + 16] = acc1[r] * inv;
    }
}

extern "C" void kernel_launch(void* const* d_in, const int* in_sizes, int n_in,
                              void* d_out, int out_size, void* d_ws, size_t ws_size,
                              hipStream_t stream) {
    const float* h   = (const float*)d_in[0];
    const int*   adj = (const int*)d_in[1];
    const float* W   = (const float*)d_in[2];
    const float* a   = (const float*)d_in[3];
    float* out = (float*)d_out;

    unsigned short* WhF  = (unsigned short*)d_ws;
    float*          src  = (float*)((char*)d_ws + 4u * 1024 * 1024);
    unsigned short* dstb = (unsigned short*)((char*)d_ws + 4u * 1024 * 1024 + 256u * 1024);

    gat_prep4<<<B_ * (N_ / 32), 256, 0, stream>>>(h, W, a, WhF, src, dstb);
    gat_main20<<<B_ * (N_ / 16), 256, 0, stream>>>(adj, WhF, src, dstb, out);
}

// Round 10
// 241.306 us; speedup vs baseline: 1.0467x; 1.0467x over previous
//
#include <hip/hip_runtime.h>

typedef short short8 __attribute__((ext_vector_type(8)));
typedef _Float16 half8 __attribute__((ext_vector_type(8)));
typedef _Float16 half2v __attribute__((ext_vector_type(2)));
typedef float floatx4 __attribute__((ext_vector_type(4)));

extern "C" __device__ _Float16 __ocml_exp2_f16(_Float16);

#define B_   8
#define N_   2048
#define FIN_ 64
#define H_   4
#define D_   32
#define HD_  128
#define ALPHA_ 0.2f
#define LOG2E_ 1.4426950408889634f

// ws layout (bytes):
//   WhF  f16 [B][H][64 chunk][2 dhalf][64 lane][8] @ 0      (4 MB)  frag-contiguous
//   src  fp32 [B][H][N] (x log2e)                  @ 4 MB   (256 KB)
//   dstb f16 [B][H][N] (x log2e)                   @ 4.25MB (128 KB)

// ---- prep: Wh = h@W; WhF fragment-layout f16, src/dst (x log2e) -------------
__global__ __launch_bounds__(256) void gat_prep4(
    const float* __restrict__ h, const float* __restrict__ W, const float* __restrict__ a,
    unsigned short* __restrict__ WhF, float* __restrict__ src, unsigned short* __restrict__ dstb)
{
    __shared__ float Ws[FIN_][HD_];
    __shared__ float hsT[FIN_][36];
    int bx = blockIdx.x;
    int b = bx >> 6;
    int n0 = (bx & 63) * 32;            // 32 graph nodes (j) per block
    int tid = threadIdx.x;

    #pragma unroll
    for (int it = 0; it < 8; ++it) {
        int idx = it * 256 + tid;
        int k = idx >> 5, c4 = (idx & 31) << 2;
        *(float4*)&Ws[k][c4] = *(const float4*)&W[k * HD_ + c4];
    }
    #pragma unroll
    for (int it = 0; it < 8; ++it) {
        int idx = it * 256 + tid;
        int r = idx >> 6, k = idx & 63;
        hsT[k][r] = h[((size_t)b * N_ + n0 + r) * FIN_ + k];
    }
    __syncthreads();

    int c = tid & 127;                  // output column = h*32+d
    int rq = tid >> 7;                  // 16-row half
    int hh = c >> 5, d = c & 31;
    float acc[16];
    #pragma unroll
    for (int r = 0; r < 16; ++r) acc[r] = 0.f;
    for (int k = 0; k < FIN_; ++k) {
        float wv = Ws[k][c];
        float4 h0 = *(const float4*)&hsT[k][rq * 16];
        float4 h1 = *(const float4*)&hsT[k][rq * 16 + 4];
        float4 h2 = *(const float4*)&hsT[k][rq * 16 + 8];
        float4 h3 = *(const float4*)&hsT[k][rq * 16 + 12];
        acc[0]  += h0.x * wv; acc[1]  += h0.y * wv; acc[2]  += h0.z * wv; acc[3]  += h0.w * wv;
        acc[4]  += h1.x * wv; acc[5]  += h1.y * wv; acc[6]  += h1.z * wv; acc[7]  += h1.w * wv;
        acc[8]  += h2.x * wv; acc[9]  += h2.y * wv; acc[10] += h2.z * wv; acc[11] += h2.w * wv;
        acc[12] += h3.x * wv; acc[13] += h3.y * wv; acc[14] += h3.z * wv; acc[15] += h3.w * wv;
    }

    // FragB write (f16): Wh[j=n0+rq*16+r][col c] -> WhF[b][hh][it][dhalf][g*16+n][e]
    {
        int half = d >> 4, n = d & 15;
        int j0 = n0 + rq * 16;
        int it0 = j0 >> 5;
        int g0 = (j0 >> 3) & 3;         // 0 or 2; spans g0, g0+1
        #pragma unroll
        for (int rr = 0; rr < 2; ++rr) {
            __attribute__((aligned(16))) unsigned pk4[4];
            #pragma unroll
            for (int q = 0; q < 4; ++q)
                pk4[q] = __builtin_bit_cast(unsigned,
                    __builtin_amdgcn_cvt_pkrtz(acc[rr * 8 + 2 * q], acc[rr * 8 + 2 * q + 1]));
            size_t fi = ((((size_t)b * H_ + hh) * 64 + it0) * 2 + half) * 64
                        + (size_t)(g0 + rr) * 16 + n;
            *(uint4*)&WhF[fi * 8] = *(uint4*)pk4;
        }
    }

    float a1v = a[hh * 64 + d];
    float a2v = a[hh * 64 + 32 + d];
    #pragma unroll
    for (int r = 0; r < 16; ++r) {
        float s1 = acc[r] * a1v;
        float s2 = acc[r] * a2v;
        #pragma unroll
        for (int off = 16; off >= 1; off >>= 1) {
            s1 += __shfl_xor(s1, off, 32);
            s2 += __shfl_xor(s2, off, 32);
        }
        if (d == 0) {
            int n = n0 + rq * 16 + r;
            src[(b * H_ + hh) * N_ + n] = s1 * LOG2E_;
            _Float16 hv = (_Float16)(s2 * LOG2E_);
            dstb[(b * H_ + hh) * N_ + n] = __builtin_bit_cast(unsigned short, hv);
        }
    }
}

// ---- main: wave = j-quarter x ALL heads. Mask built once per chunk in regs,
// consumed 4x (head-independent). No ballots, ZERO main-loop barriers
// (wave-local adj rows / dst quarter / WhF stream). 48 live accumulators make
// the schedule collapse-proof (compiler cannot reach a low-pressure regime).
// 5-barrier LDS epilogue reduces the 4 per-wave partials per head.
__global__ __launch_bounds__(256, 4) void gat_main21(
    const int* __restrict__ adj, const unsigned short* __restrict__ WhF,
    const float* __restrict__ src, const unsigned short* __restrict__ dstb,
    float* __restrict__ out)
{
    __shared__ unsigned short dsts[H_][N_];    // 16 KB; j-quarter wv staged by wave wv
    __shared__ float pbuf[4][4][64][4];        // 16 KB cross-wave reduction buffer

    int bx = blockIdx.x;
    int b  = bx >> 7;
    int i0 = (bx & 127) * 16;
    int tid = threadIdx.x;
    int wv = tid >> 6, l = tid & 63;
    int g = l >> 4, m = l & 15;
    int g8 = g << 3;

    // wave-local dst staging: wave wv stages its j-quarter for ALL heads.
    // No barrier: only this wave reads this quarter (same-wave LDS ordering).
    {
        int j0 = wv * 512;
        #pragma unroll
        for (int hh = 0; hh < 4; ++hh)
            *(uint4*)&dsts[hh][j0 + l * 8] =
                *(const uint4*)&dstb[(size_t)(b * H_ + hh) * N_ + j0 + l * 8];
    }

    // per-head src scalars (x log2e)
    half2v s2h[4];
    #pragma unroll
    for (int hh = 0; hh < 4; ++hh) {
        _Float16 sv = (_Float16)src[(b * H_ + hh) * N_ + i0 + m];
        s2h[hh][0] = sv; s2h[hh][1] = sv;
    }
    const _Float16 alf = (_Float16)0.2f;

    // per-lane adj: lane (g,m) reads row i0+m, j = (wv*16+c)*32 + g8 .. +8
    const int* adjP = adj + ((size_t)(b * N_ + i0 + m)) * N_ + wv * 512 + g8;
    // WhF: addr = (b*256 + hh*64 + wv*16 + c)*1024 + l*8 (+512 for dhalf 1)
    const unsigned short* WhBw = WhF + (((size_t)b * H_) * 64 + wv * 16) * 1024 + l * 8;
    // dv: dsts[hh][wv*512 + c*32 + g8]
    const unsigned short* dvb = &dsts[0][wv * 512 + g8];

    short8 onesS;
    #pragma unroll
    for (int q = 0; q < 8; ++q) onesS[q] = (short)0x3C00;  // f16 1.0
    half8 ones = __builtin_bit_cast(half8, onesS);

    floatx4 acc0[4], acc1[4], acc2[4];
    #pragma unroll
    for (int hh = 0; hh < 4; ++hh) {
        acc0[hh] = floatx4{0.f, 0.f, 0.f, 0.f};
        acc1[hh] = floatx4{0.f, 0.f, 0.f, 0.f};
        acc2[hh] = floatx4{0.f, 0.f, 0.f, 0.f};
    }

    // additive f16 mask pair {0,-inf} from two adj ints in {0,1} (main20-proven)
    auto mkpair = [](int px, int py) -> unsigned {
        unsigned t = (((unsigned)px) | ((unsigned)py << 16)) ^ 0x00010001u;
        return t * 0xFC00u;                    // halves independent, no carry
    };

    // prologue: flattened it2 = c*4+hh; prefetch it2=0 (c0,h0) and it2=1 (c0,h1)
    short8 bf0_1 = *(const short8*)&WhBw[0];
    short8 bf1_1 = *(const short8*)&WhBw[512];
    short8 bf0_2 = *(const short8*)&WhBw[65536];
    short8 bf1_2 = *(const short8*)&WhBw[65536 + 512];
    uint4 dv_1 = *(const uint4*)&dvb[0];
    uint4 dv_2 = *(const uint4*)&dvb[2048];
    int4 ajA0 = *(const int4*)&adjP[0];        // chunk c=0
    int4 ajA1 = *(const int4*)&adjP[4];
    int4 ajB0 = *(const int4*)&adjP[32];       // chunk c=1
    int4 ajB1 = *(const int4*)&adjP[36];

    for (int c = 0; c < 16; ++c) {
        // masks for this chunk, reused by all 4 heads
        unsigned mk[4];
        mk[0] = mkpair(ajA0.x, ajA0.y);
        mk[1] = mkpair(ajA0.z, ajA0.w);
        mk[2] = mkpair(ajA1.x, ajA1.y);
        mk[3] = mkpair(ajA1.z, ajA1.w);
        // prefetch chunk c+2 adj (clamped; clamped loads never consumed)
        int cp = (c + 2 < 16) ? (c + 2) : 15;
        int4 ajN0 = *(const int4*)&adjP[cp * 32];
        int4 ajN1 = *(const int4*)&adjP[cp * 32 + 4];

        #pragma unroll
        for (int hh = 0; hh < 4; ++hh) {
            // prefetch (it2+2) = (c + (hh>=2), (hh+2)&3); tail overreads stay
            // inside WhF/dsts (never consumed)
            int c2 = c + (hh >> 1);
            int h2 = (hh + 2) & 3;
            short8 bf0_n = *(const short8*)&WhBw[h2 * 65536 + c2 * 1024];
            short8 bf1_n = *(const short8*)&WhBw[h2 * 65536 + c2 * 1024 + 512];
            uint4  dv_n  = *(const uint4*)&dvb[h2 * 2048 + c2 * 32];

            // e-math for (c, hh)
            const unsigned* du = (const unsigned*)&dv_1;
            __attribute__((aligned(16))) unsigned pk[4];
            #pragma unroll
            for (int p = 0; p < 4; ++p) {
                half2v d2 = __builtin_bit_cast(half2v, du[p]);
                half2v e2 = s2h[hh] + d2;                       // v_pk_add_f16
                e2 = e2 + __builtin_bit_cast(half2v, mk[p]);    // + {0,-inf} mask
                half2v t2 = e2 * alf;                           // v_pk_mul_f16
                e2 = __builtin_elementwise_max(e2, t2);         // v_pk_max_f16 (lrelu)
                half2v x2;
                x2[0] = __ocml_exp2_f16(e2[0]);                 // exp2; -inf -> +0
                x2[1] = __ocml_exp2_f16(e2[1]);
                pk[p] = __builtin_bit_cast(unsigned, x2);
            }
            half8 af = __builtin_bit_cast(half8, *(uint4*)pk);
            acc0[hh] = __builtin_amdgcn_mfma_f32_16x16x32_f16(
                           af, __builtin_bit_cast(half8, bf0_1), acc0[hh], 0, 0, 0);
            acc1[hh] = __builtin_amdgcn_mfma_f32_16x16x32_f16(
                           af, __builtin_bit_cast(half8, bf1_1), acc1[hh], 0, 0, 0);
            acc2[hh] = __builtin_amdgcn_mfma_f32_16x16x32_f16(af, ones, acc2[hh], 0, 0, 0);
            // rotate depth-2 pipelines (unrolled -> renaming)
            bf0_1 = bf0_2; bf0_2 = bf0_n;
            bf1_1 = bf1_2; bf1_2 = bf1_n;
            dv_1 = dv_2;   dv_2 = dv_n;
        }
        ajA0 = ajB0; ajA1 = ajB1;
        ajB0 = ajN0; ajB1 = ajN1;
    }

    // ---- epilogue: cross-wave reduce (partial per j-quarter -> totals) ------
    __syncthreads();                           // all waves done (incl. dsts reads)
    #pragma unroll
    for (int hh = 0; hh < 4; ++hh)
        *(floatx4*)&pbuf[wv][hh][l][0] = acc2[hh];
    __syncthreads();
    floatx4 sum2 = {0.f, 0.f, 0.f, 0.f};
    #pragma unroll
    for (int w2 = 0; w2 < 4; ++w2)
        sum2 += *(const floatx4*)&pbuf[w2][wv][l][0];
    floatx4 invv;
    #pragma unroll
    for (int r = 0; r < 4; ++r) invv[r] = 1.f / sum2[r];

    __syncthreads();
    #pragma unroll
    for (int hh = 0; hh < 4; ++hh)
        *(floatx4*)&pbuf[wv][hh][l][0] = acc0[hh];
    __syncthreads();
    floatx4 s0 = {0.f, 0.f, 0.f, 0.f};
    #pragma unroll
    for (int w2 = 0; w2 < 4; ++w2)
        s0 += *(const floatx4*)&pbuf[w2][wv][l][0];
    #pragma unroll
    for (int r = 0; r < 4; ++r) {
        size_t o = ((size_t)b * N_ + i0 + g * 4 + r) * HD_ + wv * 32 + m;
        out[o] = s0[r] * invv[r];
    }

    __syncthreads();
    #pragma unroll
    for (int hh = 0; hh < 4; ++hh)
        *(floatx4*)&pbuf[wv][hh][l][0] = acc1[hh];
    __syncthreads();
    floatx4 s1 = {0.f, 0.f, 0.f, 0.f};
    #pragma unroll
    for (int w2 = 0; w2 < 4; ++w2)
        s1 += *(const floatx4*)&pbuf[w2][wv][l][0];
    #pragma unroll
    for (int r = 0; r < 4; ++r) {
        size_t o = ((size_t)b * N_ + i0 + g * 4 + r) * HD_ + wv * 32 + m + 16;
        out[o] = s1[r] * invv[r];
    }
}

extern "C" void kernel_launch(void* const* d_in, const int* in_sizes, int n_in,
                              void* d_out, int out_size, void* d_ws, size_t ws_size,
                              hipStream_t stream) {
    const float* h   = (const float*)d_in[0];
    const int*   adj = (const int*)d_in[1];
    const float* W   = (const float*)d_in[2];
    const float* a   = (const float*)d_in[3];
    float* out = (float*)d_out;

    unsigned short* WhF  = (unsigned short*)d_ws;
    float*          src  = (float*)((char*)d_ws + 4u * 1024 * 1024);
    unsigned short* dstb = (unsigned short*)((char*)d_ws + 4u * 1024 * 1024 + 256u * 1024);

    gat_prep4<<<B_ * (N_ / 32), 256, 0, stream>>>(h, W, a, WhF, src, dstb);
    gat_main21<<<B_ * (N_ / 16), 256, 0, stream>>>(adj, WhF, src, dstb, out);
}

// Round 11
// 227.566 us; speedup vs baseline: 1.1099x; 1.0604x over previous
//
#include <hip/hip_runtime.h>

typedef short short8 __attribute__((ext_vector_type(8)));
typedef _Float16 half8 __attribute__((ext_vector_type(8)));
typedef _Float16 half2v __attribute__((ext_vector_type(2)));
typedef float floatx4 __attribute__((ext_vector_type(4)));

extern "C" __device__ _Float16 __ocml_exp2_f16(_Float16);

#define B_   8
#define N_   2048
#define FIN_ 64
#define H_   4
#define D_   32
#define HD_  128
#define JH_  1024
#define ALPHA_ 0.2f
#define LOG2E_ 1.4426950408889634f

// ws layout (bytes):
//   WhF  f16 [B][H][64 chunk][2 dhalf][64 lane][8] @ 0      (4 MB)  frag-contiguous
//   src  fp32 [B][H][N] (x log2e)                  @ 4 MB   (256 KB)
//   dstb f16 [B][H][N] (x log2e)                   @ 4.25MB (128 KB)
//   pO   fp32 [2][B][N][HD]                        @ 8 MB   (16 MB)
//   pW   fp32 [2][B][H][N]                         @ 24 MB  (512 KB)

// ---- prep: Wh = h@W; WhF fragment-layout f16, src/dst (x log2e) -------------
__global__ __launch_bounds__(256) void gat_prep4(
    const float* __restrict__ h, const float* __restrict__ W, const float* __restrict__ a,
    unsigned short* __restrict__ WhF, float* __restrict__ src, unsigned short* __restrict__ dstb)
{
    __shared__ float Ws[FIN_][HD_];
    __shared__ float hsT[FIN_][36];
    int bx = blockIdx.x;
    int b = bx >> 6;
    int n0 = (bx & 63) * 32;            // 32 graph nodes (j) per block
    int tid = threadIdx.x;

    #pragma unroll
    for (int it = 0; it < 8; ++it) {
        int idx = it * 256 + tid;
        int k = idx >> 5, c4 = (idx & 31) << 2;
        *(float4*)&Ws[k][c4] = *(const float4*)&W[k * HD_ + c4];
    }
    #pragma unroll
    for (int it = 0; it < 8; ++it) {
        int idx = it * 256 + tid;
        int r = idx >> 6, k = idx & 63;
        hsT[k][r] = h[((size_t)b * N_ + n0 + r) * FIN_ + k];
    }
    __syncthreads();

    int c = tid & 127;                  // output column = h*32+d
    int rq = tid >> 7;                  // 16-row half
    int hh = c >> 5, d = c & 31;
    float acc[16];
    #pragma unroll
    for (int r = 0; r < 16; ++r) acc[r] = 0.f;
    for (int k = 0; k < FIN_; ++k) {
        float wv = Ws[k][c];
        float4 h0 = *(const float4*)&hsT[k][rq * 16];
        float4 h1 = *(const float4*)&hsT[k][rq * 16 + 4];
        float4 h2 = *(const float4*)&hsT[k][rq * 16 + 8];
        float4 h3 = *(const float4*)&hsT[k][rq * 16 + 12];
        acc[0]  += h0.x * wv; acc[1]  += h0.y * wv; acc[2]  += h0.z * wv; acc[3]  += h0.w * wv;
        acc[4]  += h1.x * wv; acc[5]  += h1.y * wv; acc[6]  += h1.z * wv; acc[7]  += h1.w * wv;
        acc[8]  += h2.x * wv; acc[9]  += h2.y * wv; acc[10] += h2.z * wv; acc[11] += h2.w * wv;
        acc[12] += h3.x * wv; acc[13] += h3.y * wv; acc[14] += h3.z * wv; acc[15] += h3.w * wv;
    }

    // FragB write (f16): Wh[j=n0+rq*16+r][col c] -> WhF[b][hh][it][dhalf][g*16+n][e]
    {
        int half = d >> 4, n = d & 15;
        int j0 = n0 + rq * 16;
        int it0 = j0 >> 5;
        int g0 = (j0 >> 3) & 3;         // 0 or 2; spans g0, g0+1
        #pragma unroll
        for (int rr = 0; rr < 2; ++rr) {
            __attribute__((aligned(16))) unsigned pk4[4];
            #pragma unroll
            for (int q = 0; q < 4; ++q)
                pk4[q] = __builtin_bit_cast(unsigned,
                    __builtin_amdgcn_cvt_pkrtz(acc[rr * 8 + 2 * q], acc[rr * 8 + 2 * q + 1]));
            size_t fi = ((((size_t)b * H_ + hh) * 64 + it0) * 2 + half) * 64
                        + (size_t)(g0 + rr) * 16 + n;
            *(uint4*)&WhF[fi * 8] = *(uint4*)pk4;
        }
    }

    float a1v = a[hh * 64 + d];
    float a2v = a[hh * 64 + 32 + d];
    #pragma unroll
    for (int r = 0; r < 16; ++r) {
        float s1 = acc[r] * a1v;
        float s2 = acc[r] * a2v;
        #pragma unroll
        for (int off = 16; off >= 1; off >>= 1) {
            s1 += __shfl_xor(s1, off, 32);
            s2 += __shfl_xor(s2, off, 32);
        }
        if (d == 0) {
            int n = n0 + rq * 16 + r;
            src[(b * H_ + hh) * N_ + n] = s1 * LOG2E_;
            _Float16 hv = (_Float16)(s2 * LOG2E_);
            dstb[(b * H_ + hh) * N_ + n] = __builtin_bit_cast(unsigned short, hv);
        }
    }
}

// ------ main: j-split x2 (grid 2048 -> 8 blocks/CU) + main14 stall fixes.
// __launch_bounds__(256,4): VGPR cap 128, compiler lands at its natural 64
// (measured main13/main18), so HW residency reaches 8 waves/SIMD WITHOUT the
// allocator strangulation that spilled main17 at bound=8 (VGPR 32, 86MB spill).
__global__ __launch_bounds__(256, 4) void gat_main22(
    const int* __restrict__ adj, const unsigned short* __restrict__ WhF,
    const float* __restrict__ src, const unsigned short* __restrict__ dstb,
    float* __restrict__ pO, float* __restrict__ pW)
{
    __shared__ unsigned short dsts[H_ * JH_];  // 8 KB (this j-half, f16)
    __shared__ unsigned adjW[16][36];          // 32 words + pad (16B-aligned rows)

    int bx = blockIdx.x;
    int b    = bx >> 8;
    int rest = bx & 255;
    int jh   = rest & 1;
    int i0   = (rest >> 1) * 16;
    int jb   = jh * JH_;
    int tid = threadIdx.x;
    int wv = tid >> 6, l = tid & 63;

    #pragma unroll
    for (int it = 0; it < 2; ++it) {           // dst half: 4096 f16 = 512 uint4
        int idx = it * 256 + tid;
        int hh = idx >> 7, off = (idx & 127) * 8;
        *(uint4*)&dsts[hh * JH_ + off] =
            *(const uint4*)&dstb[(size_t)(b * H_ + hh) * N_ + jb + off];
    }

    // adj staging: wave wv owns rows wv*4..+3 of this j-half; ballot packs 64->u64
    const int* adjBase = adj + ((size_t)(b * N_ + i0 + wv * 4)) * N_ + jb + l;

    int vals[16];                              // in-flight group: 4 rows x 4 chunks
    #pragma unroll
    for (int rr = 0; rr < 4; ++rr)
        #pragma unroll
        for (int cc = 0; cc < 4; ++cc)
            vals[rr * 4 + cc] = adjBase[rr * N_ + cc * 64];

    int h = wv, g = l >> 4, m = l & 15;
    int g8 = g << 3;
    _Float16 sv = (_Float16)src[(b * H_ + h) * N_ + i0 + m];
    half2v s2; s2[0] = sv; s2[1] = sv;
    const _Float16 alf = (_Float16)0.2f;
    // fragment-contiguous B: this half starts at chunk jh*32
    const unsigned short* WhB =
        WhF + (((size_t)(b * H_ + h) * 64 + jh * 32)) * 1024 + l * 8;
    const unsigned short* dstH = &dsts[h * JH_];

    short8 onesS;
    #pragma unroll
    for (int q = 0; q < 8; ++q) onesS[q] = (short)0x3C00;  // f16 1.0
    half8 ones = __builtin_bit_cast(half8, onesS);

    floatx4 acc0 = {0.f, 0.f, 0.f, 0.f};
    floatx4 acc1 = {0.f, 0.f, 0.f, 0.f};
    floatx4 acc2 = {0.f, 0.f, 0.f, 0.f};

    // depth-2 B-fragment prefetch (chunks 0 and 1 in flight before loop)
    short8 bf0_a = *(const short8*)&WhB[0];
    short8 bf1_a = *(const short8*)&WhB[512];
    short8 bf0_b = *(const short8*)&WhB[1024];
    short8 bf1_b = *(const short8*)&WhB[1536];
    uint4 dv_a, dv_b;                          // valid after first barrier

    for (int q = 0; q < 4; ++q) {
        // ---- ballot group q into LDS (loads already in flight)
        #pragma unroll
        for (int rr = 0; rr < 4; ++rr)
            #pragma unroll
            for (int cc = 0; cc < 4; ++cc) {
                unsigned long long mk = __ballot(vals[rr * 4 + cc] != 0);
                if (l == 0)
                    *(unsigned long long*)&adjW[wv * 4 + rr][2 * (q * 4 + cc)] = mk;
            }
        __syncthreads();                        // staging q visible to all waves

        // ---- preload ALL 8 mask words of this group (2x ds_read_b128)
        uint4 shv0 = *(const uint4*)&adjW[m][q * 8];
        uint4 shv1 = *(const uint4*)&adjW[m][q * 8 + 4];
        if (q == 0) {
            dv_a = *(const uint4*)&dstH[g8];
            dv_b = *(const uint4*)&dstH[32 + g8];
        }

        // ---- issue group q+1 adj loads (hidden behind compute below)
        if (q < 3) {
            #pragma unroll
            for (int rr = 0; rr < 4; ++rr)
                #pragma unroll
                for (int cc = 0; cc < 4; ++cc)
                    vals[rr * 4 + cc] = adjBase[rr * N_ + (q + 1) * 256 + cc * 64];
        }

        // ---- compute 8 MFMA K-chunks of group q (j in [q*256, q*256+256))
        #pragma unroll
        for (int jj = 0; jj < 8; ++jj) {
            int it = q * 8 + jj;
            // prefetch chunk it+2 (tail overreads stay inside ws, never consumed)
            int fn = (it + 2) * 1024;
            short8 bf0_n = *(const short8*)&WhB[fn];
            short8 bf1_n = *(const short8*)&WhB[fn + 512];
            int j2 = ((it + 2) << 5) + g8;
            uint4  dv_n = *(const uint4*)&dstH[(j2 < JH_) ? j2 : g8];

            unsigned sh = (jj < 4 ? ((const unsigned*)&shv0)[jj]
                                  : ((const unsigned*)&shv1)[jj - 4]) >> g8;
            const unsigned* du = (const unsigned*)&dv_a;
            __attribute__((aligned(16))) unsigned pk[4];
            #pragma unroll
            for (int c2 = 0; c2 < 4; ++c2) {
                half2v d2 = __builtin_bit_cast(half2v, du[c2]);
                half2v e2 = s2 + d2;                            // v_pk_add_f16
                half2v t2 = e2 * alf;                           // v_pk_mul_f16
                e2 = __builtin_elementwise_max(e2, t2);         // v_pk_max_f16 (lrelu)
                half2v x2;
                x2[0] = __ocml_exp2_f16(e2[0]);                 // v_exp_f16 x2
                x2[1] = __ocml_exp2_f16(e2[1]);
                unsigned mk = ((((sh >> (2 * c2 + 1)) & 1u) << 16)
                               | ((sh >> (2 * c2)) & 1u)) * 0x3C00u;  // {0,1} f16 pair
                x2 = x2 * __builtin_bit_cast(half2v, mk);       // v_pk_mul_f16 mask
                pk[c2] = __builtin_bit_cast(unsigned, x2);      // IS the A-frag pair
            }
            half8 af = __builtin_bit_cast(half8, *(uint4*)pk);
            acc0 = __builtin_amdgcn_mfma_f32_16x16x32_f16(
                       af, __builtin_bit_cast(half8, bf0_a), acc0, 0, 0, 0);
            acc1 = __builtin_amdgcn_mfma_f32_16x16x32_f16(
                       af, __builtin_bit_cast(half8, bf1_a), acc1, 0, 0, 0);
            acc2 = __builtin_amdgcn_mfma_f32_16x16x32_f16(af, ones, acc2, 0, 0, 0);
            // rotate depth-2 pipelines (unrolled -> pure renaming)
            bf0_a = bf0_b; bf0_b = bf0_n;
            bf1_a = bf1_b; bf1_b = bf1_n;
            dv_a = dv_b;   dv_b = dv_n;
        }
    }

    // partial row-sums + partial PV (C/D: col=m, row=g*4+r)
    if (m == 0) {
        #pragma unroll
        for (int r = 0; r < 4; ++r)
            pW[(((size_t)jh * B_ + b) * H_ + h) * N_ + i0 + g * 4 + r] = acc2[r];
    }
    #pragma unroll
    for (int r = 0; r < 4; ++r) {
        size_t o = ((size_t)(jh * B_ + b) * N_ + i0 + g * 4 + r) * HD_ + h * 32 + m;
        pO[o]      = acc0[r];
        pO[o + 16] = acc1[r];
    }
}

// ---------------- finalize: sum halves, divide by wsum, write out ------------
__global__ __launch_bounds__(256) void gat_fin(
    const float* __restrict__ pO, const float* __restrict__ pW, float* __restrict__ out)
{
    int gid = blockIdx.x * 256 + threadIdx.x;    // float4 index, 524288 total
    int c4 = (gid & 31) << 2;
    int i  = (gid >> 5) & (N_ - 1);
    int b  = gid >> 16;
    int hh = c4 >> 5;
    float w0 = pW[((size_t)b * H_ + hh) * N_ + i];
    float w1 = pW[(((size_t)B_ + b) * H_ + hh) * N_ + i];
    float inv = 1.f / (w0 + w1);
    size_t o = ((size_t)b * N_ + i) * HD_ + c4;
    float4 v0 = *(const float4*)&pO[o];
    float4 v1 = *(const float4*)&pO[(size_t)B_ * N_ * HD_ + o];
    float4 r;
    r.x = (v0.x + v1.x) * inv;
    r.y = (v0.y + v1.y) * inv;
    r.z = (v0.z + v1.z) * inv;
    r.w = (v0.w + v1.w) * inv;
    *(float4*)&out[o] = r;
}

extern "C" void kernel_launch(void* const* d_in, const int* in_sizes, int n_in,
                              void* d_out, int out_size, void* d_ws, size_t ws_size,
                              hipStream_t stream) {
    const float* h   = (const float*)d_in[0];
    const int*   adj = (const int*)d_in[1];
    const float* W   = (const float*)d_in[2];
    const float* a   = (const float*)d_in[3];
    float* out = (float*)d_out;

    unsigned short* WhF  = (unsigned short*)d_ws;
    float*          src  = (float*)((char*)d_ws + 4u * 1024 * 1024);
    unsigned short* dstb = (unsigned short*)((char*)d_ws + 4u * 1024 * 1024 + 256u * 1024);
    float*          pO   = (float*)((char*)d_ws + 8u * 1024 * 1024);
    float*          pW   = (float*)((char*)d_ws + 24u * 1024 * 1024);

    gat_prep4<<<B_ * (N_ / 32), 256, 0, stream>>>(h, W, a, WhF, src, dstb);
    gat_main22<<<B_ * (N_ / 16) * 2, 256, 0, stream>>>(adj, WhF, src, dstb, pO, pW);
    gat_fin<<<(B_ * N_ * HD_ / 4) / 256, 256, 0, stream>>>(pO, pW, out);
}